// Round 3
// baseline (1146.584 us; speedup 1.0000x reference)
//
#include <hip/hip_runtime.h>
#include <stdint.h>

#define N_PTS 240000
#define NV    11059200      // 2*480*360*32 voxels
#define NWORDS 172800       // NV/64 bitmap words
#define NB_PT 938           // ceil(N_PTS/256)
#define NB_WORD 675         // NWORDS/256 (exact)
#define NBLK_MLP 3750       // N_PTS/64
#define NBLK_MID 768        // fused-mid grid; <=1024 guaranteed-resident at 4 blocks/CU
#define NVB_P0  1194        // 256 weight-prep vblocks + 938 point vblocks
#define PA 264              // LDS row pitch (shorts)

typedef __bf16 bf16x8 __attribute__((ext_vector_type(8)));
typedef short  short8 __attribute__((ext_vector_type(8)));
typedef float  f32x4  __attribute__((ext_vector_type(4)));

__device__ __forceinline__ unsigned short f2bf(float f) {
  unsigned u = __builtin_bit_cast(unsigned, f);
  return (unsigned short)((u + 0x7FFFu + ((u >> 16) & 1u)) >> 16);   // RNE
}
__device__ __forceinline__ float bf2f(unsigned short h) {
  unsigned u = ((unsigned)h) << 16;
  return __builtin_bit_cast(float, u);
}

__device__ __forceinline__ unsigned block_sum(unsigned v, unsigned* s4, int t) {
  #pragma unroll
  for (int o = 32; o; o >>= 1) v += __shfl_down(v, o);
  if ((t & 63) == 0) s4[t >> 6] = v;
  __syncthreads();
  unsigned r = s4[0] + s4[1] + s4[2] + s4[3];
  __syncthreads();
  return r;
}

// ---- device-scope grid barrier (sense via generation counter). All NBLK_MID blocks are
// guaranteed co-resident: launch_bounds(256,4) => <=128 VGPR => >=4 blocks/CU => >=1024 slots.
__device__ __forceinline__ void gbar(unsigned* bar) {
  __threadfence();                                   // publish this block's writes (device scope)
  __syncthreads();
  if (threadIdx.x == 0) {
    unsigned g = __hip_atomic_load(&bar[1], __ATOMIC_ACQUIRE, __HIP_MEMORY_SCOPE_AGENT);
    unsigned a = __hip_atomic_fetch_add(&bar[0], 1u, __ATOMIC_ACQ_REL, __HIP_MEMORY_SCOPE_AGENT);
    if (a + 1u == (unsigned)NBLK_MID) {
      __hip_atomic_store(&bar[0], 0u, __ATOMIC_RELAXED, __HIP_MEMORY_SCOPE_AGENT);
      __hip_atomic_fetch_add(&bar[1], 1u, __ATOMIC_RELEASE, __HIP_MEMORY_SCOPE_AGENT);
    } else {
      while (__hip_atomic_load(&bar[1], __ATOMIC_ACQUIRE, __HIP_MEMORY_SCOPE_AGENT) == g)
        __builtin_amdgcn_s_sleep(8);
    }
  }
  __syncthreads();
}

// ================= fused middle pipeline: 7 phases, 6 grid barriers, ONE dispatch =========
// P0 weight-prep+voxelize | P1 word popcount sums | P2 unique scatter | P3 inverse+cnt
// P4 cnt sums | P5 CSR offsets | P6 plist scatter + empty-pooled fill
__global__ __launch_bounds__(256, 4) void fused_mid_kernel(
    const float* __restrict__ bng0, const float* __restrict__ bnb0, const float* __restrict__ bnm0, const float* __restrict__ bnv0,
    const float* __restrict__ bng1, const float* __restrict__ bnb1, const float* __restrict__ bnm1, const float* __restrict__ bnv1,
    const float* __restrict__ bng2, const float* __restrict__ bnb2, const float* __restrict__ bnm2, const float* __restrict__ bnv2,
    const float* __restrict__ bng3, const float* __restrict__ bnb3, const float* __restrict__ bnm3, const float* __restrict__ bnv3,
    const float* __restrict__ w1, const float* __restrict__ b1,
    const float* __restrict__ w2, const float* __restrict__ b2,
    const float* __restrict__ w3, const float* __restrict__ b3,
    const float* __restrict__ w4, const float* __restrict__ wc,
    float* __restrict__ s0, float* __restrict__ t0, float* __restrict__ w1e, float* __restrict__ be1,
    float* __restrict__ be2, float* __restrict__ be3,
    unsigned short* __restrict__ w2t, unsigned short* __restrict__ w3t, unsigned short* __restrict__ w4t,
    unsigned short* __restrict__ wct,
    const float* __restrict__ xyz, const int* __restrict__ bidx,
    unsigned* __restrict__ flatkeys, unsigned long long* __restrict__ bitmap,
    float* __restrict__ out_cat, float* __restrict__ out_unq,
    unsigned* __restrict__ bsumA, unsigned* __restrict__ wordpref, unsigned* __restrict__ unqvals,
    unsigned* __restrict__ unq_inv, unsigned* __restrict__ cnt,
    unsigned* __restrict__ bsumB, unsigned* __restrict__ offv, unsigned* __restrict__ cur,
    unsigned long long* __restrict__ plist64, const float* __restrict__ bc,
    float* __restrict__ out_pooled, unsigned* __restrict__ bar)
{
  __shared__ unsigned sh[256];
  __shared__ unsigned s4[4];
  const int t = threadIdx.x;

  // ---- P0: weight prep (vb 0..255) + per-point voxelize (vb 256..1193) ----
  for (int vb = blockIdx.x; vb < NVB_P0; vb += NBLK_MID) {
    if (vb < 256) {
      const int id = vb * 256 + t;                   // covers 65536 exactly
      { int c = id >> 8, k = id & 255; w4t[c * 256 + k] = f2bf(w4[k * 256 + c]); }
      if (id < 32768) { int c = id >> 7, k = id & 127;
        float s = bng3[c] * rsqrtf(bnv3[c] + 1e-5f);
        w3t[c * 128 + k] = f2bf(w3[k * 256 + c] * s); }
      if (id < 8192) { int c = id >> 6, k = id & 63;
        float s = bng2[c] * rsqrtf(bnv2[c] + 1e-5f);
        w2t[c * 64 + k] = f2bf(w2[k * 128 + c] * s); }
      if (id < 4096) { int c = id >> 8, k = id & 255;
        wct[c * 256 + k] = f2bf(wc[k * 16 + c]); }   // wc transposed [16][256]
      if (id < 576) { int k = id / 64, c = id % 64;
        float s = bng1[c] * rsqrtf(bnv1[c] + 1e-5f);
        w1e[k * 64 + c] = w1[k * 64 + c] * s; }
      if (id < 64)  { float s = bng1[id] * rsqrtf(bnv1[id] + 1e-5f); be1[id] = (b1[id] - bnm1[id]) * s + bnb1[id]; }
      if (id < 128) { float s = bng2[id] * rsqrtf(bnv2[id] + 1e-5f); be2[id] = (b2[id] - bnm2[id]) * s + bnb2[id]; }
      if (id < 256) { float s = bng3[id] * rsqrtf(bnv3[id] + 1e-5f); be3[id] = (b3[id] - bnm3[id]) * s + bnb3[id]; }
      if (id < 9)   { float s = bng0[id] * rsqrtf(bnv0[id] + 1e-5f); s0[id] = s; t0[id] = bnb0[id] - bnm0[id] * s; }
    } else {
      const int j = (vb - 256) * 256 + t;
      if (j < N_PTS) {
        out_unq[j] = -1.0f;                          // jnp.unique fill_value
        const float PI_F = 3.14159265358979323846f;  // == float32(np.pi)
        const float minb[3] = {0.0f, -PI_F, -4.0f};
        const float maxb[3] = {50.0f, PI_F, 2.0f};
        const float gm1[3]  = {479.0f, 359.0f, 31.0f};
        int ind[3];
        #pragma unroll
        for (int d = 0; d < 3; ++d) {
          float itv = (maxb[d] - minb[d]) / gm1[d];  // IEEE fp32 div (no fast-math)
          float x  = xyz[(size_t)j * 3 + d];
          float cl = fminf(fmaxf(x, minb[d]), maxb[d]);
          ind[d] = (int)floorf((cl - minb[d]) / itv);
        }
        const int bi = bidx[j];
        const unsigned flat = ((unsigned)(bi * 480 + ind[0]) * 360u + (unsigned)ind[1]) * 32u + (unsigned)ind[2];
        flatkeys[j] = flat;
        atomicOr(&bitmap[flat >> 6], 1ull << (flat & 63u));
        float* oc = out_cat + (size_t)j * 4;
        oc[0] = (float)bi; oc[1] = (float)ind[0]; oc[2] = (float)ind[1]; oc[3] = (float)ind[2];
      }
    }
  }
  gbar(bar);

  // ---- P1: per-256-word popcount totals ----
  for (int vb = blockIdx.x; vb < NB_WORD; vb += NBLK_MID) {
    const int w = vb * 256 + t;
    sh[t] = (unsigned)__popcll(bitmap[w]);
    __syncthreads();
    for (int s = 128; s > 0; s >>= 1) { if (t < s) sh[t] += sh[t + s]; __syncthreads(); }
    if (t == 0) bsumA[vb] = sh[0];
    __syncthreads();
  }
  gbar(bar);

  // ---- P2: unique scatter w/ inline exclusive prefix ----
  for (int vb = blockIdx.x; vb < NB_WORD; vb += NBLK_MID) {
    const int w = vb * 256 + t;
    unsigned long long word = bitmap[w];
    unsigned own = (unsigned)__popcll(word);
    sh[t] = own; __syncthreads();
    for (int off = 1; off < 256; off <<= 1) {
      unsigned v = (t >= off) ? sh[t - off] : 0u;
      __syncthreads(); sh[t] += v; __syncthreads();
    }
    unsigned v = 0;                                  // brute-force prefix over L2-hot totals
    for (int i = t; i < vb; i += 256) v += bsumA[i];
    const unsigned excl = block_sum(v, s4, t);
    unsigned r = excl + sh[t] - own;                 // global exclusive prefix
    wordpref[w] = r;
    while (word) {
      int bit = __builtin_ctzll(word);
      unsigned id = (unsigned)w * 64u + (unsigned)bit;
      unqvals[r] = id;
      out_unq[r] = (float)id;                        // exact: id < 2^24
      ++r;
      word &= word - 1;
    }
    __syncthreads();
  }
  gbar(bar);

  // ---- P3: inverse indices + segment sizes ----
  for (int vb = blockIdx.x; vb < NB_PT; vb += NBLK_MID) {
    const int j = vb * 256 + t;
    if (j < N_PTS) {
      const unsigned f = flatkeys[j];
      const unsigned w = f >> 6, b = f & 63u;
      const unsigned r = wordpref[w] + (unsigned)__popcll(bitmap[w] & ((1ull << b) - 1ull));
      unq_inv[j] = r;
      atomicAdd(&cnt[r], 1u);
    }
  }
  gbar(bar);

  // ---- P4: per-256-cnt totals ----
  for (int vb = blockIdx.x; vb < NB_PT; vb += NBLK_MID) {
    const int j = vb * 256 + t;
    sh[t] = (j < N_PTS) ? cnt[j] : 0u;
    __syncthreads();
    for (int s = 128; s > 0; s >>= 1) { if (t < s) sh[t] += sh[t + s]; __syncthreads(); }
    if (t == 0) bsumB[vb] = sh[0];
    __syncthreads();
  }
  gbar(bar);

  // ---- P5: CSR offsets w/ inline exclusive prefix ----
  for (int vb = blockIdx.x; vb < NB_PT; vb += NBLK_MID) {
    const int j = vb * 256 + t;
    unsigned own = (j < N_PTS) ? cnt[j] : 0u;
    sh[t] = own; __syncthreads();
    for (int o = 1; o < 256; o <<= 1) {
      unsigned v = (t >= o) ? sh[t - o] : 0u;
      __syncthreads(); sh[t] += v; __syncthreads();
    }
    unsigned v = 0;
    for (int i = t; i < vb; i += 256) v += bsumB[i];
    const unsigned excl = block_sum(v, s4, t);
    if (j < N_PTS) { unsigned e = excl + sh[t] - own; offv[j] = e; cur[j] = e; }
    __syncthreads();
  }
  gbar(bar);

  // ---- P6: plist scatter (packed seg<<32|j) + empty-segment pooled fill ----
  for (int vb = blockIdx.x; vb < NB_PT; vb += NBLK_MID) {
    const int j = vb * 256 + t;
    if (j < N_PTS) {
      const unsigned r = unq_inv[j];
      plist64[atomicAdd(&cur[r], 1u)] = ((unsigned long long)r << 32) | (unsigned)j;
      if (cnt[j] == 0) {
        #pragma unroll
        for (int c = 0; c < 16; ++c) out_pooled[(size_t)j * 16 + c] = fmaxf(bc[c], 0.f);
      }
    }
  }
}

// ---- block-wide GEMM stage, column-strip waves, SWAPPED-D epilogue (b64 LDS writes) ----
// mfma(w_frag, x_frag): D row'=quad*4+r = OUT COLUMN, D col=l15 = OUT ROW (within mt tile).
// Weight frags in a depth-2 ring; s_setprio(1) around the MFMA cluster.
template<int K, int C, bool RELU, bool MIDB>
__device__ __forceinline__ void gemm_stage(
    const unsigned short* __restrict__ Wt,     // [C][K] bf16, global (L2-hot)
    const float* __restrict__ bias,            // [C]
    const unsigned short* in,                  // LDS, pitch PA (col-offset base)
    unsigned short* outp,                      // LDS, pitch PA (may overlap in)
    int wave, int l15, int quad)
{
  constexpr int KC = K / 32;
  constexpr int NT = C / 64;                   // 16-col tiles per wave (weights read ONCE/block)
  f32x4 acc[4][NT];
  #pragma unroll
  for (int mt = 0; mt < 4; ++mt)
    #pragma unroll
    for (int nt = 0; nt < NT; ++nt) acc[mt][nt] = (f32x4){0.f, 0.f, 0.f, 0.f};
  const unsigned short* wp[NT];
  #pragma unroll
  for (int nt = 0; nt < NT; ++nt)
    wp[nt] = Wt + (size_t)(wave * 16 * NT + nt * 16 + l15) * K + quad * 8;
  bf16x8 b0[NT], b1r[NT], b2r[NT];
  #pragma unroll
  for (int nt = 0; nt < NT; ++nt)
    b0[nt] = __builtin_bit_cast(bf16x8, *(const short8*)(wp[nt]));
  if (KC > 1) {
    #pragma unroll
    for (int nt = 0; nt < NT; ++nt)
      b1r[nt] = __builtin_bit_cast(bf16x8, *(const short8*)(wp[nt] + 32));
  }
  #pragma unroll
  for (int kc = 0; kc < KC; ++kc) {
    if (kc + 2 < KC) {
      #pragma unroll
      for (int nt = 0; nt < NT; ++nt)
        b2r[nt] = __builtin_bit_cast(bf16x8, *(const short8*)(wp[nt] + (kc + 2) * 32));
    }
    __builtin_amdgcn_s_setprio(1);
    #pragma unroll
    for (int mt = 0; mt < 4; ++mt) {
      bf16x8 a = __builtin_bit_cast(bf16x8, *(const short8*)&in[(mt * 16 + l15) * PA + kc * 32 + quad * 8]);
      #pragma unroll
      for (int nt = 0; nt < NT; ++nt)
        acc[mt][nt] = __builtin_amdgcn_mfma_f32_16x16x32_bf16(b0[nt], a, acc[mt][nt], 0, 0, 0);
    }
    __builtin_amdgcn_s_setprio(0);
    #pragma unroll
    for (int nt = 0; nt < NT; ++nt) { b0[nt] = b1r[nt]; b1r[nt] = b2r[nt]; }
  }
  if (MIDB) __syncthreads();                   // reads drained before overlapping writes
  #pragma unroll
  for (int mt = 0; mt < 4; ++mt)
    #pragma unroll
    for (int nt = 0; nt < NT; ++nt) {
      const int cbase = wave * 16 * NT + nt * 16 + quad * 4;
      const f32x4 bs = *(const f32x4*)&bias[cbase];
      unsigned short h[4];
      #pragma unroll
      for (int r = 0; r < 4; ++r) {
        float y = acc[mt][nt][r] + bs[r];
        if (RELU) y = fmaxf(y, 0.f);
        h[r] = f2bf(y);
      }
      uint2 pk; pk.x = (unsigned)h[0] | ((unsigned)h[1] << 16);
      pk.y = (unsigned)h[2] | ((unsigned)h[3] << 16);
      *(uint2*)&outp[(mt * 16 + l15) * PA + cbase] = pk;   // ds_write_b64
    }
  __syncthreads();
}

// ---------------- fused MLP + sparse segment-max fixup + compression + labels ----
__global__ __launch_bounds__(256, 3) void mlp_pool_kernel(
    const float* __restrict__ ptfea, const float* __restrict__ xyz, const int* __restrict__ shuf,
    const unsigned long long* __restrict__ plist64,
    const unsigned* __restrict__ offv, const unsigned* __restrict__ cnt,
    const int* __restrict__ ptlab, const unsigned* __restrict__ unqvals,
    const float* __restrict__ s0, const float* __restrict__ t0,
    const float* __restrict__ w1e, const float* __restrict__ be1,
    const unsigned short* __restrict__ w2t, const float* __restrict__ be2,
    const unsigned short* __restrict__ w3t, const float* __restrict__ be3,
    const unsigned short* __restrict__ w4t, const float* __restrict__ b4,
    const unsigned short* __restrict__ wct, const float* __restrict__ bc,
    unsigned short* __restrict__ partials, float* __restrict__ out_pooled,
    float* __restrict__ out_lab)
{
  __shared__ __align__(16) unsigned short buf[64 * PA];
  __shared__ int segs[64];
  __shared__ int jrows[64];
  __shared__ int s_alast;
  __shared__ int s_nrun;
  __shared__ unsigned short s_runs[32];              // (r<<8)|e for runs with len>1
  __shared__ unsigned char s_lead[64], s_comp[64];
  const int tid  = threadIdx.x;
  const int wave = tid >> 6, lane = tid & 63;
  const int l15 = lane & 15, quad = lane >> 4;
  const int row0 = blockIdx.x * 64;

  if (tid == 0) { s_alast = 0; s_nrun = 0; }
  if (lane < 16) {                                   // wave-local write; same-wave read below
    const int r = wave * 16 + lane;
    const unsigned long long v = plist64[row0 + r];
    jrows[r] = (int)(unsigned)v;
    segs[r]  = (int)(unsigned)(v >> 32);
  }

  // ---- stage 0: features + bn0 + layer1 (scalar fp32); 4 lanes/row, wave-local rows ----
  {
    const int r = wave * 16 + (lane >> 2), part = lane & 3;
    const int sj = shuf[jrows[r]];
    const float PI_F = 3.14159265358979323846f;
    const float minb[3] = {0.0f, -PI_F, -4.0f};
    const float maxb[3] = {50.0f, PI_F, 2.0f};
    const float gm1[3]  = {479.0f, 359.0f, 31.0f};
    float x0[9];
    #pragma unroll
    for (int d = 0; d < 3; ++d) {
      float itv = (maxb[d] - minb[d]) / gm1[d];
      float x   = xyz[(size_t)sj * 3 + d];
      float cl  = fminf(fmaxf(x, minb[d]), maxb[d]);
      float fi  = floorf((cl - minb[d]) / itv);
      float center = (fi + 0.5f) * itv + minb[d];
      x0[d] = (x - center) * s0[d] + t0[d];           // bn0 folded
    }
    #pragma unroll
    for (int d = 0; d < 6; ++d) x0[3 + d] = ptfea[(size_t)sj * 6 + d] * s0[3 + d] + t0[3 + d];
    unsigned short h[16];
    #pragma unroll
    for (int ci = 0; ci < 16; ++ci) {
      float acc = be1[part * 16 + ci];
      #pragma unroll
      for (int k = 0; k < 9; ++k) acc += x0[k] * w1e[k * 64 + part * 16 + ci];
      h[ci] = f2bf(fmaxf(acc, 0.0f));
    }
    *(short8*)&buf[r * PA + part * 16]     = *(short8*)&h[0];
    *(short8*)&buf[r * PA + part * 16 + 8] = *(short8*)&h[8];
  }
  __syncthreads();                                   // B1: h1 + segs/jrows visible

  // ---- wave 0: run analysis + labels for complete runs (overlaps waves 1-3's L2 stage;
  //      s_* consumed only after L4, several barriers later) ----
  if (tid < 64) {
    const int r = tid;
    bool lead = (r == 0) || (segs[r] != segs[r - 1]);
    s_lead[r] = lead ? 1 : 0;
    unsigned char comp = 0;
    int e = r + 1;
    if (lead) {
      atomicMax(&s_alast, r);
      while (e < 64 && segs[e] == segs[r]) ++e;
      const unsigned s = (unsigned)segs[r];
      comp = (offv[s] == (unsigned)(row0 + r) && offv[s] + cnt[s] == (unsigned)(row0 + e)) ? 1 : 0;
    }
    s_comp[r] = comp;
    if (comp) {                                      // label argmax: first max = smallest label
      int bestl;
      if (e - r == 1) bestl = ptlab[jrows[r]];
      else {
        int bestc = 0; bestl = 32;
        for (int i = r; i < e; ++i) {
          const int li = ptlab[jrows[i]];
          int cc = 0;
          for (int k2 = r; k2 < e; ++k2) cc += (ptlab[jrows[k2]] == li) ? 1 : 0;
          if (cc > bestc || (cc == bestc && li < bestl)) { bestc = cc; bestl = li; }
        }
      }
      out_lab[unqvals[segs[r]]] = (float)bestl;
    }
    const bool multi = lead && (e - r) > 1;
    unsigned long long mm = __ballot(multi);
    if (multi) {
      int idx = (int)__popcll(mm & ((1ull << r) - 1ull));
      s_runs[idx] = (unsigned short)((r << 8) | e);
    }
    if (tid == 0) s_nrun = (int)__popcll(mm);
  }

  // ---- L2 [64->128] cols 0->136 (disjoint: no mid barrier); L3 [128->256] 136->0; L4 in-place ----
  gemm_stage< 64, 128, true,  false>(w2t, be2, buf,       buf + 136, wave, l15, quad);
  gemm_stage<128, 256, true,  true >(w3t, be3, buf + 136, buf,       wave, l15, quad);
  gemm_stage<256, 256, false, true >(w4t, b4,  buf,       buf,       wave, l15, quad);

  // ---- sparse fixup: per multi-run, column-thread computes run max into the leader row ----
  {
    const int n = s_nrun;
    for (int i = 0; i < n; ++i) {
      const int re = s_runs[i];
      const int r = re >> 8, e = re & 255;
      float m = bf2f(buf[r * PA + tid]);
      for (int rr = r + 1; rr < e; ++rr) m = fmaxf(m, bf2f(buf[rr * PA + tid]));
      buf[r * PA + tid] = f2bf(m);
    }
  }
  __syncthreads();

  // ---- boundary partials (first/last incomplete runs; rows 0 and alast are leaders) ----
  {
    const int c = tid;
    const int alast = s_alast;
    const size_t b2 = (size_t)blockIdx.x * 2;
    if (!s_comp[0])     partials[b2 * 256 + c]       = buf[0 * PA + c];
    if (!s_comp[alast]) partials[(b2 + 1) * 256 + c] = buf[alast * PA + c];
  }

  // ---- compression: pooled[rows wave*16+l15, 256] @ wct^T; swapped-D -> float4 stores ----
  {
    const unsigned short* wp = wct + l15 * 256 + quad * 8;
    bf16x8 wv[8];
    #pragma unroll
    for (int kc = 0; kc < 8; ++kc)
      wv[kc] = __builtin_bit_cast(bf16x8, *(const short8*)(wp + kc * 32));
    f32x4 acc = (f32x4){0.f, 0.f, 0.f, 0.f};
    #pragma unroll
    for (int kc = 0; kc < 8; ++kc) {
      bf16x8 x = __builtin_bit_cast(bf16x8, *(const short8*)&buf[(wave * 16 + l15) * PA + kc * 32 + quad * 8]);
      acc = __builtin_amdgcn_mfma_f32_16x16x32_bf16(wv[kc], x, acc, 0, 0, 0);
    }
    const int r1 = wave * 16 + l15;                  // pooled row (D col = l15)
    if (s_lead[r1] && s_comp[r1]) {
      const f32x4 bcv = *(const f32x4*)&bc[quad * 4];
      f32x4 v;
      #pragma unroll
      for (int r = 0; r < 4; ++r) v[r] = fmaxf(acc[r] + bcv[r], 0.f);   // cols quad*4+r
      *(f32x4*)&out_pooled[(size_t)segs[r1] * 16 + quad * 4] = v;
    }
  }
}

// ---------------- merge block-spanning segments from partials (+ their labels) ----
__global__ __launch_bounds__(256) void merge_kernel(
    const unsigned long long* __restrict__ plist64,
    const unsigned* __restrict__ offv, const unsigned* __restrict__ cnt,
    const unsigned short* __restrict__ partials,
    const int* __restrict__ ptlab, const unsigned* __restrict__ unqvals,
    const float* __restrict__ wc, const float* __restrict__ bc,
    float* __restrict__ out_pooled, float* __restrict__ out_lab)
{
  __shared__ float pooled[256];
  __shared__ float psum[256];
  const int b = blockIdx.x;
  const unsigned s = (unsigned)(plist64[(size_t)b * 64 + 63] >> 32);
  const unsigned o = offv[s], e = o + cnt[s];
  if ((o >> 6) != (unsigned)b) return;              // owner = block where segment starts
  if (e <= (unsigned)(b + 1) * 64) return;          // doesn't span a boundary
  const int B1 = (int)((e - 1) >> 6);
  const int c = threadIdx.x;
  float m = bf2f(partials[((size_t)2 * b + 1) * 256 + c]);    // head partial (last run of b)
  for (int bb = b + 1; bb <= B1; ++bb)
    m = fmaxf(m, bf2f(partials[(size_t)2 * bb * 256 + c]));   // tails (first run of bb)
  pooled[c] = m;
  __syncthreads();
  const int co = c & 15, kg = c >> 4;
  float p = 0.f;
  #pragma unroll
  for (int k = kg * 16; k < kg * 16 + 16; ++k) p += pooled[k] * wc[k * 16 + co];
  psum[c] = p;
  __syncthreads();
  if (c < 16) {
    float acc = bc[c];
    #pragma unroll
    for (int g = 0; g < 16; ++g) acc += psum[g * 16 + c];
    out_pooled[(size_t)s * 16 + c] = fmaxf(acc, 0.f);
  }
  if (c == 0) {                                     // label argmax over the spanning segment
    int bestc = 0, bestl = 32;
    for (unsigned i = o; i < e; ++i) {
      const int li = ptlab[(unsigned)plist64[i]];
      int cc = 0;
      for (unsigned k2 = o; k2 < e; ++k2) cc += (ptlab[(unsigned)plist64[k2]] == li) ? 1 : 0;
      if (cc > bestc || (cc == bestc && li < bestl)) { bestc = cc; bestl = li; }
    }
    out_lab[unqvals[s]] = (float)bestl;
  }
}

extern "C" void kernel_launch(void* const* d_in, const int* in_sizes, int n_in,
                              void* d_out, int out_size, void* d_ws, size_t ws_size,
                              hipStream_t stream)
{
  const float* pt_fea = (const float*)d_in[0];
  const float* xyz    = (const float*)d_in[1];
  const int*   bidx   = (const int*)d_in[2];
  const int*   ptlab  = (const int*)d_in[3];
  const int*   shuf   = (const int*)d_in[4];
  const float* bng0 = (const float*)d_in[5],  *bnb0 = (const float*)d_in[6],  *bnm0 = (const float*)d_in[7],  *bnv0 = (const float*)d_in[8];
  const float* bng1 = (const float*)d_in[9],  *bnb1 = (const float*)d_in[10], *bnm1 = (const float*)d_in[11], *bnv1 = (const float*)d_in[12];
  const float* bng2 = (const float*)d_in[13], *bnb2 = (const float*)d_in[14], *bnm2 = (const float*)d_in[15], *bnv2 = (const float*)d_in[16];
  const float* bng3 = (const float*)d_in[17], *bnb3 = (const float*)d_in[18], *bnm3 = (const float*)d_in[19], *bnv3 = (const float*)d_in[20];
  const float* w1 = (const float*)d_in[21], *b1 = (const float*)d_in[22];
  const float* w2 = (const float*)d_in[23], *b2 = (const float*)d_in[24];
  const float* w3 = (const float*)d_in[25], *b3 = (const float*)d_in[26];
  const float* w4 = (const float*)d_in[27], *b4 = (const float*)d_in[28];
  const float* wc = (const float*)d_in[29], *bc = (const float*)d_in[30];

  float* out        = (float*)d_out;                // outputs int64/f32/int32 -> float32 buffer
  float* out_unq    = out;                          // [240000]
  float* out_pooled = out + 240000;                 // [240000,16]
  float* out_lab    = out + 4080000;                // [2,480,360,32]
  float* out_cat    = out + 15139200;               // [240000,4]

  char* wsb = (char*)d_ws;
  size_t o = 0;
  auto alloc = [&](size_t bytes) -> void* { void* p = wsb + o; o = (o + bytes + 255) & ~(size_t)255; return p; };
  // zero-init region (single memset): bitmap | cnt | barrier
  unsigned long long* bitmap = (unsigned long long*)alloc((size_t)NWORDS * 8);
  unsigned* cnt    = (unsigned*)alloc((size_t)N_PTS * 4);
  unsigned* bar    = (unsigned*)alloc(2 * 4);
  const size_t zero_bytes = o;
  float* s0  = (float*)alloc(9 * 4);
  float* t0  = (float*)alloc(9 * 4);
  float* w1e = (float*)alloc(576 * 4);
  float* be1 = (float*)alloc(64 * 4);
  float* be2 = (float*)alloc(128 * 4);
  float* be3 = (float*)alloc(256 * 4);
  unsigned short* w2t = (unsigned short*)alloc(8192 * 2);
  unsigned short* w3t = (unsigned short*)alloc(32768 * 2);
  unsigned short* w4t = (unsigned short*)alloc(65536 * 2);
  unsigned short* wct = (unsigned short*)alloc(4096 * 2);
  unsigned* flatkeys = (unsigned*)alloc((size_t)N_PTS * 4);
  unsigned* unq_inv  = (unsigned*)alloc((size_t)N_PTS * 4);
  unsigned* unqvals  = (unsigned*)alloc((size_t)N_PTS * 4);
  unsigned* offv     = (unsigned*)alloc((size_t)N_PTS * 4);
  unsigned* cur      = (unsigned*)alloc((size_t)N_PTS * 4);
  unsigned long long* plist64 = (unsigned long long*)alloc((size_t)N_PTS * 8);
  unsigned* wordpref = (unsigned*)alloc((size_t)NWORDS * 4);
  unsigned* bsumA    = (unsigned*)alloc(NB_WORD * 4);
  unsigned* bsumB    = (unsigned*)alloc(NB_PT * 4);
  unsigned short* partials = (unsigned short*)alloc((size_t)NBLK_MLP * 2 * 256 * 2);
  // total ~14 MB

  hipMemsetAsync(bitmap, 0, zero_bytes, stream);
  hipMemsetAsync(out_lab, 0, (size_t)NV * 4, stream);       // float 0.0f == all-zero bytes

  fused_mid_kernel<<<NBLK_MID, 256, 0, stream>>>(
      bng0, bnb0, bnm0, bnv0, bng1, bnb1, bnm1, bnv1,
      bng2, bnb2, bnm2, bnv2, bng3, bnb3, bnm3, bnv3,
      w1, b1, w2, b2, w3, b3, w4, wc,
      s0, t0, w1e, be1, be2, be3, w2t, w3t, w4t, wct,
      xyz, bidx, flatkeys, bitmap, out_cat, out_unq,
      bsumA, wordpref, unqvals, unq_inv, cnt, bsumB, offv, cur,
      plist64, bc, out_pooled, bar);
  mlp_pool_kernel<<<NBLK_MLP, 256, 0, stream>>>(pt_fea, xyz, shuf, plist64, offv, cnt,
                                                ptlab, unqvals,
                                                s0, t0, w1e, be1, w2t, be2, w3t, be3, w4t, b4,
                                                wct, bc, partials, out_pooled, out_lab);
  merge_kernel<<<NBLK_MLP, 256, 0, stream>>>(plist64, offv, cnt, partials,
                                             ptlab, unqvals, wc, bc, out_pooled, out_lab);
}

// Round 4
// 679.465 us; speedup vs baseline: 1.6875x; 1.6875x over previous
//
#include <hip/hip_runtime.h>
#include <stdint.h>

#define N_PTS 240000
#define NV    11059200      // 2*480*360*32 voxels
#define NWORDS 172800       // NV/64 bitmap words
#define NB_PT 938           // ceil(N_PTS/256)
#define NB_WORD 675         // NWORDS/256 (exact)
#define NBLK_MLP 3750       // row-tiles (merge grid)
#define NPERS 625           // persistent mlp blocks
#define TILES 6             // row-tiles per persistent block (625*6 = 3750)
#define PA 264              // LDS row pitch (shorts)

typedef __bf16 bf16x8 __attribute__((ext_vector_type(8)));
typedef short  short8 __attribute__((ext_vector_type(8)));
typedef float  f32x4  __attribute__((ext_vector_type(4)));

__device__ __forceinline__ unsigned short f2bf(float f) {
  unsigned u = __builtin_bit_cast(unsigned, f);
  return (unsigned short)((u + 0x7FFFu + ((u >> 16) & 1u)) >> 16);   // RNE
}
__device__ __forceinline__ float bf2f(unsigned short h) {
  unsigned u = ((unsigned)h) << 16;
  return __builtin_bit_cast(float, u);
}

__device__ __forceinline__ unsigned block_sum(unsigned v, unsigned* s4, int t) {
  #pragma unroll
  for (int o = 32; o; o >>= 1) v += __shfl_down(v, o);
  if ((t & 63) == 0) s4[t >> 6] = v;
  __syncthreads();
  unsigned r = s4[0] + s4[1] + s4[2] + s4[3];
  __syncthreads();
  return r;
}

// ---------------- fused: weight prep (blocks 0..255) + per-point voxelize (blocks 256..1193) ----
__global__ void prep_vox_kernel(
    const float* __restrict__ bng0, const float* __restrict__ bnb0, const float* __restrict__ bnm0, const float* __restrict__ bnv0,
    const float* __restrict__ bng1, const float* __restrict__ bnb1, const float* __restrict__ bnm1, const float* __restrict__ bnv1,
    const float* __restrict__ bng2, const float* __restrict__ bnb2, const float* __restrict__ bnm2, const float* __restrict__ bnv2,
    const float* __restrict__ bng3, const float* __restrict__ bnb3, const float* __restrict__ bnm3, const float* __restrict__ bnv3,
    const float* __restrict__ w1, const float* __restrict__ b1,
    const float* __restrict__ w2, const float* __restrict__ b2,
    const float* __restrict__ w3, const float* __restrict__ b3,
    const float* __restrict__ w4, const float* __restrict__ wc,
    float* __restrict__ s0, float* __restrict__ t0, float* __restrict__ w1e, float* __restrict__ be1,
    float* __restrict__ be2, float* __restrict__ be3,
    unsigned short* __restrict__ w2t, unsigned short* __restrict__ w3t, unsigned short* __restrict__ w4t,
    unsigned short* __restrict__ wct,
    const float* __restrict__ xyz, const int* __restrict__ bidx,
    unsigned* __restrict__ flatkeys, unsigned long long* __restrict__ bitmap,
    float* __restrict__ out_cat, float* __restrict__ out_unq)
{
  if (blockIdx.x < 256) {
    const int id = blockIdx.x * 256 + threadIdx.x;   // covers 65536 exactly
    { int c = id >> 8, k = id & 255; w4t[c * 256 + k] = f2bf(w4[k * 256 + c]); }
    if (id < 32768) { int c = id >> 7, k = id & 127;
      float s = bng3[c] * rsqrtf(bnv3[c] + 1e-5f);
      w3t[c * 128 + k] = f2bf(w3[k * 256 + c] * s); }
    if (id < 8192) { int c = id >> 6, k = id & 63;
      float s = bng2[c] * rsqrtf(bnv2[c] + 1e-5f);
      w2t[c * 64 + k] = f2bf(w2[k * 128 + c] * s); }
    if (id < 4096) { int c = id >> 8, k = id & 255;
      wct[c * 256 + k] = f2bf(wc[k * 16 + c]); }     // wc transposed [16][256]
    if (id < 576) { int k = id / 64, c = id % 64;
      float s = bng1[c] * rsqrtf(bnv1[c] + 1e-5f);
      w1e[k * 64 + c] = w1[k * 64 + c] * s; }
    if (id < 64)  { float s = bng1[id] * rsqrtf(bnv1[id] + 1e-5f); be1[id] = (b1[id] - bnm1[id]) * s + bnb1[id]; }
    if (id < 128) { float s = bng2[id] * rsqrtf(bnv2[id] + 1e-5f); be2[id] = (b2[id] - bnm2[id]) * s + bnb2[id]; }
    if (id < 256) { float s = bng3[id] * rsqrtf(bnv3[id] + 1e-5f); be3[id] = (b3[id] - bnm3[id]) * s + bnb3[id]; }
    if (id < 9)   { float s = bng0[id] * rsqrtf(bnv0[id] + 1e-5f); s0[id] = s; t0[id] = bnb0[id] - bnm0[id] * s; }
    return;
  }
  const int j = (blockIdx.x - 256) * 256 + threadIdx.x;
  if (j >= N_PTS) return;
  out_unq[j] = -1.0f;                               // jnp.unique fill_value
  const float PI_F = 3.14159265358979323846f;       // == float32(np.pi)
  const float minb[3] = {0.0f, -PI_F, -4.0f};
  const float maxb[3] = {50.0f, PI_F, 2.0f};
  const float gm1[3]  = {479.0f, 359.0f, 31.0f};
  int ind[3];
  #pragma unroll
  for (int d = 0; d < 3; ++d) {
    float itv = (maxb[d] - minb[d]) / gm1[d];       // IEEE fp32 div (no fast-math)
    float x  = xyz[(size_t)j * 3 + d];
    float cl = fminf(fmaxf(x, minb[d]), maxb[d]);
    ind[d] = (int)floorf((cl - minb[d]) / itv);
  }
  const int bi = bidx[j];
  const unsigned flat = ((unsigned)(bi * 480 + ind[0]) * 360u + (unsigned)ind[1]) * 32u + (unsigned)ind[2];
  flatkeys[j] = flat;
  atomicOr(&bitmap[flat >> 6], 1ull << (flat & 63u));
  float* oc = out_cat + (size_t)j * 4;
  oc[0] = (float)bi; oc[1] = (float)ind[0]; oc[2] = (float)ind[1]; oc[3] = (float)ind[2];
}

// ---------------- per-block popcount totals ----
__global__ void reduce_words(const unsigned long long* __restrict__ bm, unsigned* __restrict__ bsums) {
  __shared__ unsigned sh[256];
  const int w = blockIdx.x * 256 + threadIdx.x;     // exact coverage
  sh[threadIdx.x] = (unsigned)__popcll(bm[w]);
  __syncthreads();
  for (int s = 128; s > 0; s >>= 1) { if (threadIdx.x < s) sh[threadIdx.x] += sh[threadIdx.x + s]; __syncthreads(); }
  if (threadIdx.x == 0) bsums[blockIdx.x] = sh[0];
}

// ---------------- unique scatter w/ inline exclusive prefix (bsums are RAW totals) ----
__global__ __launch_bounds__(256) void scatter_unq(
    const unsigned long long* __restrict__ bm, const unsigned* __restrict__ bsums,
    unsigned* __restrict__ wordpref, unsigned* __restrict__ unqvals, float* __restrict__ out_unq)
{
  __shared__ unsigned sh[256];
  __shared__ unsigned s4[4];
  const int t = threadIdx.x, b = blockIdx.x;
  const int w = b * 256 + t;
  unsigned long long word = bm[w];
  unsigned own = (unsigned)__popcll(word);
  sh[t] = own; __syncthreads();
  for (int off = 1; off < 256; off <<= 1) {
    unsigned v = (t >= off) ? sh[t - off] : 0u;
    __syncthreads(); sh[t] += v; __syncthreads();
  }
  unsigned v = 0;                                   // brute-force prefix over L2-hot totals
  for (int i = t; i < b; i += 256) v += bsums[i];
  const unsigned excl = block_sum(v, s4, t);
  unsigned r = excl + sh[t] - own;                  // global exclusive prefix
  wordpref[w] = r;
  while (word) {
    int bit = __builtin_ctzll(word);
    unsigned id = (unsigned)w * 64u + (unsigned)bit;
    unqvals[r] = id;
    out_unq[r] = (float)id;                         // exact: id < 2^24
    ++r;
    word &= word - 1;
  }
}

// ---------------- inverse indices + segment sizes ----
__global__ void inv_kernel(const unsigned* __restrict__ flatkeys, const unsigned long long* __restrict__ bm,
                           const unsigned* __restrict__ wordpref,
                           unsigned* __restrict__ unq_inv, unsigned* __restrict__ cnt) {
  const int j = blockIdx.x * 256 + threadIdx.x;
  if (j >= N_PTS) return;
  const unsigned f = flatkeys[j];
  const unsigned w = f >> 6, b = f & 63u;
  const unsigned r = wordpref[w] + (unsigned)__popcll(bm[w] & ((1ull << b) - 1ull));
  unq_inv[j] = r;
  atomicAdd(&cnt[r], 1u);
}

// ---------------- per-block cnt totals ----
__global__ void reduce_cnt(const unsigned* __restrict__ cnt, unsigned* __restrict__ bsums) {
  __shared__ unsigned sh[256];
  const int j = blockIdx.x * 256 + threadIdx.x;
  sh[threadIdx.x] = (j < N_PTS) ? cnt[j] : 0u;
  __syncthreads();
  for (int s = 128; s > 0; s >>= 1) { if (threadIdx.x < s) sh[threadIdx.x] += sh[threadIdx.x + s]; __syncthreads(); }
  if (threadIdx.x == 0) bsums[blockIdx.x] = sh[0];
}

// ---------------- CSR offsets w/ inline exclusive prefix (bsums are RAW totals) ----
__global__ __launch_bounds__(256) void scan_cnt(
    const unsigned* __restrict__ cnt, const unsigned* __restrict__ bsums,
    unsigned* __restrict__ off, unsigned* __restrict__ cur)
{
  __shared__ unsigned sh[256];
  __shared__ unsigned s4[4];
  const int t = threadIdx.x, b = blockIdx.x;
  const int j = b * 256 + t;
  unsigned own = (j < N_PTS) ? cnt[j] : 0u;
  sh[t] = own; __syncthreads();
  for (int o = 1; o < 256; o <<= 1) {
    unsigned v = (t >= o) ? sh[t - o] : 0u;
    __syncthreads(); sh[t] += v; __syncthreads();
  }
  unsigned v = 0;
  for (int i = t; i < b; i += 256) v += bsums[i];
  const unsigned excl = block_sum(v, s4, t);
  if (j < N_PTS) { unsigned e = excl + sh[t] - own; off[j] = e; cur[j] = e; }
}

// ---------------- plist scatter (packed seg<<32|j) + empty-segment pooled fill ----
__global__ void plist_fill_kernel(const unsigned* __restrict__ unq_inv, unsigned* __restrict__ cur,
                                  unsigned long long* __restrict__ plist64,
                                  const unsigned* __restrict__ cnt, const float* __restrict__ bc,
                                  float* __restrict__ out_pooled) {
  const int j = blockIdx.x * 256 + threadIdx.x;
  if (j >= N_PTS) return;
  const unsigned r = unq_inv[j];
  plist64[atomicAdd(&cur[r], 1u)] = ((unsigned long long)r << 32) | (unsigned)j;
  if (cnt[j] == 0) {
    #pragma unroll
    for (int c = 0; c < 16; ++c) out_pooled[(size_t)j * 16 + c] = fmaxf(bc[c], 0.f);
  }
}

// ---- block-wide GEMM stage, column-strip waves, SWAPPED-D epilogue (b64 LDS writes) ----
// mfma(w_frag, x_frag): D row'=quad*4+r = OUT COLUMN, D col=l15 = OUT ROW (within mt tile).
// Weight frags in a depth-2 ring; s_setprio(1) around the MFMA cluster.
template<int K, int C, bool RELU, bool MIDB>
__device__ __forceinline__ void gemm_stage(
    const unsigned short* __restrict__ Wt,     // [C][K] bf16, global (L2-hot)
    const float* __restrict__ bias,            // [C]
    const unsigned short* in,                  // LDS, pitch PA (col-offset base)
    unsigned short* outp,                      // LDS, pitch PA (may overlap in)
    int wave, int l15, int quad)
{
  constexpr int KC = K / 32;
  constexpr int NT = C / 64;                   // 16-col tiles per wave (weights read ONCE/block)
  f32x4 acc[4][NT];
  #pragma unroll
  for (int mt = 0; mt < 4; ++mt)
    #pragma unroll
    for (int nt = 0; nt < NT; ++nt) acc[mt][nt] = (f32x4){0.f, 0.f, 0.f, 0.f};
  const unsigned short* wp[NT];
  #pragma unroll
  for (int nt = 0; nt < NT; ++nt)
    wp[nt] = Wt + (size_t)(wave * 16 * NT + nt * 16 + l15) * K + quad * 8;
  bf16x8 b0[NT], b1r[NT], b2r[NT];
  #pragma unroll
  for (int nt = 0; nt < NT; ++nt)
    b0[nt] = __builtin_bit_cast(bf16x8, *(const short8*)(wp[nt]));
  if (KC > 1) {
    #pragma unroll
    for (int nt = 0; nt < NT; ++nt)
      b1r[nt] = __builtin_bit_cast(bf16x8, *(const short8*)(wp[nt] + 32));
  }
  #pragma unroll
  for (int kc = 0; kc < KC; ++kc) {
    if (kc + 2 < KC) {
      #pragma unroll
      for (int nt = 0; nt < NT; ++nt)
        b2r[nt] = __builtin_bit_cast(bf16x8, *(const short8*)(wp[nt] + (kc + 2) * 32));
    }
    __builtin_amdgcn_s_setprio(1);
    #pragma unroll
    for (int mt = 0; mt < 4; ++mt) {
      bf16x8 a = __builtin_bit_cast(bf16x8, *(const short8*)&in[(mt * 16 + l15) * PA + kc * 32 + quad * 8]);
      #pragma unroll
      for (int nt = 0; nt < NT; ++nt)
        acc[mt][nt] = __builtin_amdgcn_mfma_f32_16x16x32_bf16(b0[nt], a, acc[mt][nt], 0, 0, 0);
    }
    __builtin_amdgcn_s_setprio(0);
    #pragma unroll
    for (int nt = 0; nt < NT; ++nt) { b0[nt] = b1r[nt]; b1r[nt] = b2r[nt]; }
  }
  if (MIDB) __syncthreads();                   // reads drained before overlapping writes
  #pragma unroll
  for (int mt = 0; mt < 4; ++mt)
    #pragma unroll
    for (int nt = 0; nt < NT; ++nt) {
      const int cbase = wave * 16 * NT + nt * 16 + quad * 4;
      const f32x4 bs = *(const f32x4*)&bias[cbase];
      unsigned short h[4];
      #pragma unroll
      for (int r = 0; r < 4; ++r) {
        float y = acc[mt][nt][r] + bs[r];
        if (RELU) y = fmaxf(y, 0.f);
        h[r] = f2bf(y);
      }
      uint2 pk; pk.x = (unsigned)h[0] | ((unsigned)h[1] << 16);
      pk.y = (unsigned)h[2] | ((unsigned)h[3] << 16);
      *(uint2*)&outp[(mt * 16 + l15) * PA + cbase] = pk;   // ds_write_b64
    }
  __syncthreads();
}

// ---------------- persistent fused MLP: 625 blocks x 6 row-tiles, cross-tile prefetch ----
// Next tile's gather chain (plist -> shuf -> xyz/ptfea) issued in stages DURING current
// tile's GEMMs so each link's L2/HBM latency hides under a GEMM stage. Per-tile meta
// arrays double-buffered [2] so next-tile state never waits on current-tile consumers.
__global__ __launch_bounds__(256, 3) void mlp_pool_kernel(
    const float* __restrict__ ptfea, const float* __restrict__ xyz, const int* __restrict__ shuf,
    const unsigned long long* __restrict__ plist64,
    const unsigned* __restrict__ offv, const unsigned* __restrict__ cnt,
    const int* __restrict__ ptlab, const unsigned* __restrict__ unqvals,
    const float* __restrict__ s0, const float* __restrict__ t0,
    const float* __restrict__ w1e, const float* __restrict__ be1,
    const unsigned short* __restrict__ w2t, const float* __restrict__ be2,
    const unsigned short* __restrict__ w3t, const float* __restrict__ be3,
    const unsigned short* __restrict__ w4t, const float* __restrict__ b4,
    const unsigned short* __restrict__ wct, const float* __restrict__ bc,
    unsigned short* __restrict__ partials, float* __restrict__ out_pooled,
    float* __restrict__ out_lab)
{
  __shared__ __align__(16) unsigned short buf[64 * PA];
  __shared__ int segs[2][64];
  __shared__ int jrows[2][64];
  __shared__ int s_alast[2];
  __shared__ int s_nrun[2];
  __shared__ unsigned short s_runs[2][32];           // (r<<8)|e for runs with len>1
  __shared__ unsigned char s_lead[2][64], s_comp[2][64];
  const int tid  = threadIdx.x;
  const int wave = tid >> 6, lane = tid & 63;
  const int l15 = lane & 15, quad = lane >> 4;
  const int gr   = wave * 16 + (lane >> 2);          // stage-0 row of this thread
  const int part = lane & 3;                         // stage-0 channel group

  const float PI_F = 3.14159265358979323846f;
  const float minb[3] = {0.0f, -PI_F, -4.0f};
  const float maxb[3] = {50.0f, PI_F, 2.0f};
  const float gm1[3]  = {479.0f, 359.0f, 31.0f};

  // ---- prologue: tile 0 gather chain (serial, once) ----
  int jr, sg, sj;
  float xz[3], fe[6];
  {
    const unsigned long long v = plist64[(size_t)blockIdx.x * TILES * 64 + gr];
    jr = (int)(unsigned)v; sg = (int)(unsigned)(v >> 32);
    sj = shuf[jr];
    #pragma unroll
    for (int d = 0; d < 3; ++d) xz[d] = xyz[(size_t)sj * 3 + d];
    #pragma unroll
    for (int d = 0; d < 6; ++d) fe[d] = ptfea[(size_t)sj * 6 + d];
  }

  for (int tile = 0; tile < TILES; ++tile) {
    const int btile = blockIdx.x * TILES + tile;
    const int row0  = btile * 64;
    const int pb    = tile & 1;
    const bool hn   = (tile + 1 < TILES);

    if (tid == 0) { s_alast[pb] = 0; s_nrun[pb] = 0; }
    if (part == 0) { jrows[pb][gr] = jr; segs[pb][gr] = sg; }   // wave-local write

    // ---- stage 0: bn0 fold + layer1 (scalar fp32) from registers; 4 lanes/row ----
    {
      float x0[9];
      #pragma unroll
      for (int d = 0; d < 3; ++d) {
        float itv = (maxb[d] - minb[d]) / gm1[d];
        float cl  = fminf(fmaxf(xz[d], minb[d]), maxb[d]);
        float fi  = floorf((cl - minb[d]) / itv);
        float center = (fi + 0.5f) * itv + minb[d];
        x0[d] = (xz[d] - center) * s0[d] + t0[d];     // bn0 folded
      }
      #pragma unroll
      for (int d = 0; d < 6; ++d) x0[3 + d] = fe[d] * s0[3 + d] + t0[3 + d];
      unsigned short h[16];
      #pragma unroll
      for (int ci = 0; ci < 16; ++ci) {
        float acc = be1[part * 16 + ci];
        #pragma unroll
        for (int k = 0; k < 9; ++k) acc += x0[k] * w1e[k * 64 + part * 16 + ci];
        h[ci] = f2bf(fmaxf(acc, 0.0f));
      }
      *(short8*)&buf[gr * PA + part * 16]     = *(short8*)&h[0];
      *(short8*)&buf[gr * PA + part * 16 + 8] = *(short8*)&h[8];
    }
    __syncthreads();                                 // B1: h1 + segs/jrows visible

    // ---- prefetch link 1: next tile's plist row (in flight under analysis + L2 stage) ----
    unsigned long long vn = 0;
    if (hn) vn = plist64[(size_t)row0 + 64 + gr];

    // ---- wave 0: run analysis + labels for complete runs (overlaps waves 1-3's L2 stage) ----
    if (tid < 64) {
      const int r = tid;
      bool lead = (r == 0) || (segs[pb][r] != segs[pb][r - 1]);
      s_lead[pb][r] = lead ? 1 : 0;
      unsigned char comp = 0;
      int e = r + 1;
      if (lead) {
        atomicMax(&s_alast[pb], r);
        while (e < 64 && segs[pb][e] == segs[pb][r]) ++e;
        const unsigned s = (unsigned)segs[pb][r];
        comp = (offv[s] == (unsigned)(row0 + r) && offv[s] + cnt[s] == (unsigned)(row0 + e)) ? 1 : 0;
      }
      s_comp[pb][r] = comp;
      if (comp) {                                    // label argmax: first max = smallest label
        int bestl;
        if (e - r == 1) bestl = ptlab[jrows[pb][r]];
        else {
          int bestc = 0; bestl = 32;
          for (int i = r; i < e; ++i) {
            const int li = ptlab[jrows[pb][i]];
            int cc = 0;
            for (int k2 = r; k2 < e; ++k2) cc += (ptlab[jrows[pb][k2]] == li) ? 1 : 0;
            if (cc > bestc || (cc == bestc && li < bestl)) { bestc = cc; bestl = li; }
          }
        }
        out_lab[unqvals[segs[pb][r]]] = (float)bestl;
      }
      const bool multi = lead && (e - r) > 1;
      unsigned long long mm = __ballot(multi);
      if (multi) {
        int idx = (int)__popcll(mm & ((1ull << r) - 1ull));
        s_runs[pb][idx] = (unsigned short)((r << 8) | e);
      }
      if (tid == 0) s_nrun[pb] = (int)__popcll(mm);
    }

    // ---- L2 [64->128] cols 0->136 (disjoint: no mid barrier) ----
    gemm_stage< 64, 128, true,  false>(w2t, be2, buf,       buf + 136, wave, l15, quad);

    // ---- prefetch link 2: next tile's shuffle index ----
    int jrn = 0, sgn = 0, sjn = 0;
    if (hn) {
      jrn = (int)(unsigned)vn; sgn = (int)(unsigned)(vn >> 32);
      sjn = shuf[jrn];
    }

    // ---- L3 [128->256] cols 136->0 ----
    gemm_stage<128, 256, true,  true >(w3t, be3, buf + 136, buf,       wave, l15, quad);

    // ---- prefetch link 3: next tile's xyz/ptfea rows (in flight under L4) ----
    float xzn[3] = {0.f, 0.f, 0.f}, fen[6] = {0.f, 0.f, 0.f, 0.f, 0.f, 0.f};
    if (hn) {
      #pragma unroll
      for (int d = 0; d < 3; ++d) xzn[d] = xyz[(size_t)sjn * 3 + d];
      #pragma unroll
      for (int d = 0; d < 6; ++d) fen[d] = ptfea[(size_t)sjn * 6 + d];
    }

    // ---- L4 [256->256] in-place ----
    gemm_stage<256, 256, false, true >(w4t, b4,  buf,       buf,       wave, l15, quad);

    // ---- sparse fixup: per multi-run, column-thread computes run max into the leader row ----
    {
      const int n = s_nrun[pb];
      for (int i = 0; i < n; ++i) {
        const int re = s_runs[pb][i];
        const int r = re >> 8, e = re & 255;
        float m = bf2f(buf[r * PA + tid]);
        for (int rr = r + 1; rr < e; ++rr) m = fmaxf(m, bf2f(buf[rr * PA + tid]));
        buf[r * PA + tid] = f2bf(m);
      }
    }
    __syncthreads();

    // ---- boundary partials (first/last incomplete runs; rows 0 and alast are leaders) ----
    {
      const int c = tid;
      const int alast = s_alast[pb];
      const size_t b2 = (size_t)btile * 2;
      if (!s_comp[pb][0])     partials[b2 * 256 + c]       = buf[0 * PA + c];
      if (!s_comp[pb][alast]) partials[(b2 + 1) * 256 + c] = buf[alast * PA + c];
    }

    // ---- compression: pooled[rows wave*16+l15, 256] @ wct^T; swapped-D -> float4 stores ----
    {
      const unsigned short* wp = wct + l15 * 256 + quad * 8;
      bf16x8 wv[8];
      #pragma unroll
      for (int kc = 0; kc < 8; ++kc)
        wv[kc] = __builtin_bit_cast(bf16x8, *(const short8*)(wp + kc * 32));
      f32x4 acc = (f32x4){0.f, 0.f, 0.f, 0.f};
      #pragma unroll
      for (int kc = 0; kc < 8; ++kc) {
        bf16x8 x = __builtin_bit_cast(bf16x8, *(const short8*)&buf[(wave * 16 + l15) * PA + kc * 32 + quad * 8]);
        acc = __builtin_amdgcn_mfma_f32_16x16x32_bf16(wv[kc], x, acc, 0, 0, 0);
      }
      const int r1 = wave * 16 + l15;                // pooled row (D col = l15)
      if (s_lead[pb][r1] && s_comp[pb][r1]) {
        const f32x4 bcv = *(const f32x4*)&bc[quad * 4];
        f32x4 v;
        #pragma unroll
        for (int r = 0; r < 4; ++r) v[r] = fmaxf(acc[r] + bcv[r], 0.f);   // cols quad*4+r
        *(f32x4*)&out_pooled[(size_t)segs[pb][r1] * 16 + quad * 4] = v;
      }
    }

    // ---- rotate prefetch -> current; barrier: buf fully consumed before next stage-0 writes ----
    jr = jrn; sg = sgn; sj = sjn;
    #pragma unroll
    for (int d = 0; d < 3; ++d) xz[d] = xzn[d];
    #pragma unroll
    for (int d = 0; d < 6; ++d) fe[d] = fen[d];
    __syncthreads();
  }
}

// ---------------- merge block-spanning segments from partials (+ their labels) ----
__global__ __launch_bounds__(256) void merge_kernel(
    const unsigned long long* __restrict__ plist64,
    const unsigned* __restrict__ offv, const unsigned* __restrict__ cnt,
    const unsigned short* __restrict__ partials,
    const int* __restrict__ ptlab, const unsigned* __restrict__ unqvals,
    const float* __restrict__ wc, const float* __restrict__ bc,
    float* __restrict__ out_pooled, float* __restrict__ out_lab)
{
  __shared__ float pooled[256];
  __shared__ float psum[256];
  const int b = blockIdx.x;
  const unsigned s = (unsigned)(plist64[(size_t)b * 64 + 63] >> 32);
  const unsigned o = offv[s], e = o + cnt[s];
  if ((o >> 6) != (unsigned)b) return;              // owner = block where segment starts
  if (e <= (unsigned)(b + 1) * 64) return;          // doesn't span a boundary
  const int B1 = (int)((e - 1) >> 6);
  const int c = threadIdx.x;
  float m = bf2f(partials[((size_t)2 * b + 1) * 256 + c]);    // head partial (last run of b)
  for (int bb = b + 1; bb <= B1; ++bb)
    m = fmaxf(m, bf2f(partials[(size_t)2 * bb * 256 + c]));   // tails (first run of bb)
  pooled[c] = m;
  __syncthreads();
  const int co = c & 15, kg = c >> 4;
  float p = 0.f;
  #pragma unroll
  for (int k = kg * 16; k < kg * 16 + 16; ++k) p += pooled[k] * wc[k * 16 + co];
  psum[c] = p;
  __syncthreads();
  if (c < 16) {
    float acc = bc[c];
    #pragma unroll
    for (int g = 0; g < 16; ++g) acc += psum[g * 16 + c];
    out_pooled[(size_t)s * 16 + c] = fmaxf(acc, 0.f);
  }
  if (c == 0) {                                     // label argmax over the spanning segment
    int bestc = 0, bestl = 32;
    for (unsigned i = o; i < e; ++i) {
      const int li = ptlab[(unsigned)plist64[i]];
      int cc = 0;
      for (unsigned k2 = o; k2 < e; ++k2) cc += (ptlab[(unsigned)plist64[k2]] == li) ? 1 : 0;
      if (cc > bestc || (cc == bestc && li < bestl)) { bestc = cc; bestl = li; }
    }
    out_lab[unqvals[s]] = (float)bestl;
  }
}

extern "C" void kernel_launch(void* const* d_in, const int* in_sizes, int n_in,
                              void* d_out, int out_size, void* d_ws, size_t ws_size,
                              hipStream_t stream)
{
  const float* pt_fea = (const float*)d_in[0];
  const float* xyz    = (const float*)d_in[1];
  const int*   bidx   = (const int*)d_in[2];
  const int*   ptlab  = (const int*)d_in[3];
  const int*   shuf   = (const int*)d_in[4];
  const float* bng0 = (const float*)d_in[5],  *bnb0 = (const float*)d_in[6],  *bnm0 = (const float*)d_in[7],  *bnv0 = (const float*)d_in[8];
  const float* bng1 = (const float*)d_in[9],  *bnb1 = (const float*)d_in[10], *bnm1 = (const float*)d_in[11], *bnv1 = (const float*)d_in[12];
  const float* bng2 = (const float*)d_in[13], *bnb2 = (const float*)d_in[14], *bnm2 = (const float*)d_in[15], *bnv2 = (const float*)d_in[16];
  const float* bng3 = (const float*)d_in[17], *bnb3 = (const float*)d_in[18], *bnm3 = (const float*)d_in[19], *bnv3 = (const float*)d_in[20];
  const float* w1 = (const float*)d_in[21], *b1 = (const float*)d_in[22];
  const float* w2 = (const float*)d_in[23], *b2 = (const float*)d_in[24];
  const float* w3 = (const float*)d_in[25], *b3 = (const float*)d_in[26];
  const float* w4 = (const float*)d_in[27], *b4 = (const float*)d_in[28];
  const float* wc = (const float*)d_in[29], *bc = (const float*)d_in[30];

  float* out        = (float*)d_out;                // outputs int64/f32/int32 -> float32 buffer
  float* out_unq    = out;                          // [240000]
  float* out_pooled = out + 240000;                 // [240000,16]
  float* out_lab    = out + 4080000;                // [2,480,360,32]
  float* out_cat    = out + 15139200;               // [240000,4]

  char* wsb = (char*)d_ws;
  size_t o = 0;
  auto alloc = [&](size_t bytes) -> void* { void* p = wsb + o; o = (o + bytes + 255) & ~(size_t)255; return p; };
  // zero-init region (single memset): bitmap | cnt
  unsigned long long* bitmap = (unsigned long long*)alloc((size_t)NWORDS * 8);
  unsigned* cnt    = (unsigned*)alloc((size_t)N_PTS * 4);
  const size_t zero_bytes = o;
  float* s0  = (float*)alloc(9 * 4);
  float* t0  = (float*)alloc(9 * 4);
  float* w1e = (float*)alloc(576 * 4);
  float* be1 = (float*)alloc(64 * 4);
  float* be2 = (float*)alloc(128 * 4);
  float* be3 = (float*)alloc(256 * 4);
  unsigned short* w2t = (unsigned short*)alloc(8192 * 2);
  unsigned short* w3t = (unsigned short*)alloc(32768 * 2);
  unsigned short* w4t = (unsigned short*)alloc(65536 * 2);
  unsigned short* wct = (unsigned short*)alloc(4096 * 2);
  unsigned* flatkeys = (unsigned*)alloc((size_t)N_PTS * 4);
  unsigned* unq_inv  = (unsigned*)alloc((size_t)N_PTS * 4);
  unsigned* unqvals  = (unsigned*)alloc((size_t)N_PTS * 4);
  unsigned* offv     = (unsigned*)alloc((size_t)N_PTS * 4);
  unsigned* cur      = (unsigned*)alloc((size_t)N_PTS * 4);
  unsigned long long* plist64 = (unsigned long long*)alloc((size_t)N_PTS * 8);
  unsigned* wordpref = (unsigned*)alloc((size_t)NWORDS * 4);
  unsigned* bsumA    = (unsigned*)alloc(NB_WORD * 4);
  unsigned* bsumB    = (unsigned*)alloc(NB_PT * 4);
  unsigned short* partials = (unsigned short*)alloc((size_t)NBLK_MLP * 2 * 256 * 2);
  // total ~14 MB

  hipMemsetAsync(bitmap, 0, zero_bytes, stream);
  hipMemsetAsync(out_lab, 0, (size_t)NV * 4, stream);       // float 0.0f == all-zero bytes

  prep_vox_kernel<<<256 + NB_PT, 256, 0, stream>>>(
      bng0, bnb0, bnm0, bnv0, bng1, bnb1, bnm1, bnv1,
      bng2, bnb2, bnm2, bnv2, bng3, bnb3, bnm3, bnv3,
      w1, b1, w2, b2, w3, b3, w4, wc,
      s0, t0, w1e, be1, be2, be3, w2t, w3t, w4t, wct,
      xyz, bidx, flatkeys, bitmap, out_cat, out_unq);
  reduce_words<<<NB_WORD, 256, 0, stream>>>(bitmap, bsumA);
  scatter_unq<<<NB_WORD, 256, 0, stream>>>(bitmap, bsumA, wordpref, unqvals, out_unq);
  inv_kernel<<<NB_PT, 256, 0, stream>>>(flatkeys, bitmap, wordpref, unq_inv, cnt);
  reduce_cnt<<<NB_PT, 256, 0, stream>>>(cnt, bsumB);
  scan_cnt<<<NB_PT, 256, 0, stream>>>(cnt, bsumB, offv, cur);
  plist_fill_kernel<<<NB_PT, 256, 0, stream>>>(unq_inv, cur, plist64, cnt, bc, out_pooled);
  mlp_pool_kernel<<<NPERS, 256, 0, stream>>>(pt_fea, xyz, shuf, plist64, offv, cnt,
                                             ptlab, unqvals,
                                             s0, t0, w1e, be1, w2t, be2, w3t, be3, w4t, b4,
                                             wct, bc, partials, out_pooled, out_lab);
  merge_kernel<<<NBLK_MLP, 256, 0, stream>>>(plist64, offv, cnt, partials,
                                             ptlab, unqvals, wc, bc, out_pooled, out_lab);
}

// Round 5
// 438.636 us; speedup vs baseline: 2.6140x; 1.5490x over previous
//
#include <hip/hip_runtime.h>
#include <stdint.h>

#define N_PTS 240000
#define NV    11059200      // 2*480*360*32 voxels
#define NWORDS 172800       // NV/64 bitmap words
#define NB_PT 938           // ceil(N_PTS/256)
#define NB_WORD 675         // NWORDS/256 (exact)
#define NSEG_BLK 7500       // 32-row tiles (mlp + merge grids)
#define PA 264              // LDS row pitch (shorts)

typedef __bf16 bf16x8 __attribute__((ext_vector_type(8)));
typedef short  short8 __attribute__((ext_vector_type(8)));
typedef float  f32x4  __attribute__((ext_vector_type(4)));

__device__ __forceinline__ unsigned short f2bf(float f) {
  unsigned u = __builtin_bit_cast(unsigned, f);
  return (unsigned short)((u + 0x7FFFu + ((u >> 16) & 1u)) >> 16);   // RNE
}
__device__ __forceinline__ float bf2f(unsigned short h) {
  unsigned u = ((unsigned)h) << 16;
  return __builtin_bit_cast(float, u);
}

__device__ __forceinline__ unsigned block_sum(unsigned v, unsigned* s4, int t) {
  #pragma unroll
  for (int o = 32; o; o >>= 1) v += __shfl_down(v, o);
  if ((t & 63) == 0) s4[t >> 6] = v;
  __syncthreads();
  unsigned r = s4[0] + s4[1] + s4[2] + s4[3];
  __syncthreads();
  return r;
}

// ---------------- fused: weight prep (blocks 0..255) + per-point voxelize (blocks 256..1193) ----
__global__ void prep_vox_kernel(
    const float* __restrict__ bng0, const float* __restrict__ bnb0, const float* __restrict__ bnm0, const float* __restrict__ bnv0,
    const float* __restrict__ bng1, const float* __restrict__ bnb1, const float* __restrict__ bnm1, const float* __restrict__ bnv1,
    const float* __restrict__ bng2, const float* __restrict__ bnb2, const float* __restrict__ bnm2, const float* __restrict__ bnv2,
    const float* __restrict__ bng3, const float* __restrict__ bnb3, const float* __restrict__ bnm3, const float* __restrict__ bnv3,
    const float* __restrict__ w1, const float* __restrict__ b1,
    const float* __restrict__ w2, const float* __restrict__ b2,
    const float* __restrict__ w3, const float* __restrict__ b3,
    const float* __restrict__ w4, const float* __restrict__ wc,
    float* __restrict__ s0, float* __restrict__ t0, float* __restrict__ w1e, float* __restrict__ be1,
    float* __restrict__ be2, float* __restrict__ be3,
    unsigned short* __restrict__ w2t, unsigned short* __restrict__ w3t, unsigned short* __restrict__ w4t,
    unsigned short* __restrict__ wct,
    const float* __restrict__ xyz, const int* __restrict__ bidx,
    unsigned* __restrict__ flatkeys, unsigned long long* __restrict__ bitmap,
    float* __restrict__ out_cat, float* __restrict__ out_unq)
{
  if (blockIdx.x < 256) {
    const int id = blockIdx.x * 256 + threadIdx.x;   // covers 65536 exactly
    { int c = id >> 8, k = id & 255; w4t[c * 256 + k] = f2bf(w4[k * 256 + c]); }
    if (id < 32768) { int c = id >> 7, k = id & 127;
      float s = bng3[c] * rsqrtf(bnv3[c] + 1e-5f);
      w3t[c * 128 + k] = f2bf(w3[k * 256 + c] * s); }
    if (id < 8192) { int c = id >> 6, k = id & 63;
      float s = bng2[c] * rsqrtf(bnv2[c] + 1e-5f);
      w2t[c * 64 + k] = f2bf(w2[k * 128 + c] * s); }
    if (id < 4096) { int c = id >> 8, k = id & 255;
      wct[c * 256 + k] = f2bf(wc[k * 16 + c]); }     // wc transposed [16][256]
    if (id < 576) { int k = id / 64, c = id % 64;
      float s = bng1[c] * rsqrtf(bnv1[c] + 1e-5f);
      w1e[k * 64 + c] = w1[k * 64 + c] * s; }
    if (id < 64)  { float s = bng1[id] * rsqrtf(bnv1[id] + 1e-5f); be1[id] = (b1[id] - bnm1[id]) * s + bnb1[id]; }
    if (id < 128) { float s = bng2[id] * rsqrtf(bnv2[id] + 1e-5f); be2[id] = (b2[id] - bnm2[id]) * s + bnb2[id]; }
    if (id < 256) { float s = bng3[id] * rsqrtf(bnv3[id] + 1e-5f); be3[id] = (b3[id] - bnm3[id]) * s + bnb3[id]; }
    if (id < 9)   { float s = bng0[id] * rsqrtf(bnv0[id] + 1e-5f); s0[id] = s; t0[id] = bnb0[id] - bnm0[id] * s; }
    return;
  }
  const int j = (blockIdx.x - 256) * 256 + threadIdx.x;
  if (j >= N_PTS) return;
  out_unq[j] = -1.0f;                               // jnp.unique fill_value
  const float PI_F = 3.14159265358979323846f;       // == float32(np.pi)
  const float minb[3] = {0.0f, -PI_F, -4.0f};
  const float maxb[3] = {50.0f, PI_F, 2.0f};
  const float gm1[3]  = {479.0f, 359.0f, 31.0f};
  int ind[3];
  #pragma unroll
  for (int d = 0; d < 3; ++d) {
    float itv = (maxb[d] - minb[d]) / gm1[d];       // IEEE fp32 div (no fast-math)
    float x  = xyz[(size_t)j * 3 + d];
    float cl = fminf(fmaxf(x, minb[d]), maxb[d]);
    ind[d] = (int)floorf((cl - minb[d]) / itv);
  }
  const int bi = bidx[j];
  const unsigned flat = ((unsigned)(bi * 480 + ind[0]) * 360u + (unsigned)ind[1]) * 32u + (unsigned)ind[2];
  flatkeys[j] = flat;
  atomicOr(&bitmap[flat >> 6], 1ull << (flat & 63u));
  float* oc = out_cat + (size_t)j * 4;
  oc[0] = (float)bi; oc[1] = (float)ind[0]; oc[2] = (float)ind[1]; oc[3] = (float)ind[2];
}

// ---------------- per-block popcount totals ----
__global__ void reduce_words(const unsigned long long* __restrict__ bm, unsigned* __restrict__ bsums) {
  __shared__ unsigned sh[256];
  const int w = blockIdx.x * 256 + threadIdx.x;     // exact coverage
  sh[threadIdx.x] = (unsigned)__popcll(bm[w]);
  __syncthreads();
  for (int s = 128; s > 0; s >>= 1) { if (threadIdx.x < s) sh[threadIdx.x] += sh[threadIdx.x + s]; __syncthreads(); }
  if (threadIdx.x == 0) bsums[blockIdx.x] = sh[0];
}

// ---------------- unique scatter w/ inline exclusive prefix (bsums are RAW totals) ----
__global__ __launch_bounds__(256) void scatter_unq(
    const unsigned long long* __restrict__ bm, const unsigned* __restrict__ bsums,
    unsigned* __restrict__ wordpref, unsigned* __restrict__ unqvals, float* __restrict__ out_unq)
{
  __shared__ unsigned sh[256];
  __shared__ unsigned s4[4];
  const int t = threadIdx.x, b = blockIdx.x;
  const int w = b * 256 + t;
  unsigned long long word = bm[w];
  unsigned own = (unsigned)__popcll(word);
  sh[t] = own; __syncthreads();
  for (int off = 1; off < 256; off <<= 1) {
    unsigned v = (t >= off) ? sh[t - off] : 0u;
    __syncthreads(); sh[t] += v; __syncthreads();
  }
  unsigned v = 0;                                   // brute-force prefix over L2-hot totals
  for (int i = t; i < b; i += 256) v += bsums[i];
  const unsigned excl = block_sum(v, s4, t);
  unsigned r = excl + sh[t] - own;                  // global exclusive prefix
  wordpref[w] = r;
  while (word) {
    int bit = __builtin_ctzll(word);
    unsigned id = (unsigned)w * 64u + (unsigned)bit;
    unqvals[r] = id;
    out_unq[r] = (float)id;                         // exact: id < 2^24
    ++r;
    word &= word - 1;
  }
}

// ---------------- inverse indices + segment sizes ----
__global__ void inv_kernel(const unsigned* __restrict__ flatkeys, const unsigned long long* __restrict__ bm,
                           const unsigned* __restrict__ wordpref,
                           unsigned* __restrict__ unq_inv, unsigned* __restrict__ cnt) {
  const int j = blockIdx.x * 256 + threadIdx.x;
  if (j >= N_PTS) return;
  const unsigned f = flatkeys[j];
  const unsigned w = f >> 6, b = f & 63u;
  const unsigned r = wordpref[w] + (unsigned)__popcll(bm[w] & ((1ull << b) - 1ull));
  unq_inv[j] = r;
  atomicAdd(&cnt[r], 1u);
}

// ---------------- per-block cnt totals ----
__global__ void reduce_cnt(const unsigned* __restrict__ cnt, unsigned* __restrict__ bsums) {
  __shared__ unsigned sh[256];
  const int j = blockIdx.x * 256 + threadIdx.x;
  sh[threadIdx.x] = (j < N_PTS) ? cnt[j] : 0u;
  __syncthreads();
  for (int s = 128; s > 0; s >>= 1) { if (threadIdx.x < s) sh[threadIdx.x] += sh[threadIdx.x + s]; __syncthreads(); }
  if (threadIdx.x == 0) bsums[blockIdx.x] = sh[0];
}

// ---------------- CSR offsets w/ inline exclusive prefix (bsums are RAW totals) ----
__global__ __launch_bounds__(256) void scan_cnt(
    const unsigned* __restrict__ cnt, const unsigned* __restrict__ bsums,
    unsigned* __restrict__ off, unsigned* __restrict__ cur)
{
  __shared__ unsigned sh[256];
  __shared__ unsigned s4[4];
  const int t = threadIdx.x, b = blockIdx.x;
  const int j = b * 256 + t;
  unsigned own = (j < N_PTS) ? cnt[j] : 0u;
  sh[t] = own; __syncthreads();
  for (int o = 1; o < 256; o <<= 1) {
    unsigned v = (t >= o) ? sh[t - o] : 0u;
    __syncthreads(); sh[t] += v; __syncthreads();
  }
  unsigned v = 0;
  for (int i = t; i < b; i += 256) v += bsums[i];
  const unsigned excl = block_sum(v, s4, t);
  if (j < N_PTS) { unsigned e = excl + sh[t] - own; off[j] = e; cur[j] = e; }
}

// ---------------- plist scatter (packed seg<<32|j) + empty-segment pooled fill ----
__global__ void plist_fill_kernel(const unsigned* __restrict__ unq_inv, unsigned* __restrict__ cur,
                                  unsigned long long* __restrict__ plist64,
                                  const unsigned* __restrict__ cnt, const float* __restrict__ bc,
                                  float* __restrict__ out_pooled) {
  const int j = blockIdx.x * 256 + threadIdx.x;
  if (j >= N_PTS) return;
  const unsigned r = unq_inv[j];
  plist64[atomicAdd(&cur[r], 1u)] = ((unsigned long long)r << 32) | (unsigned)j;
  if (cnt[j] == 0) {
    #pragma unroll
    for (int c = 0; c < 16; ++c) out_pooled[(size_t)j * 16 + c] = fmaxf(bc[c], 0.f);
  }
}

// ---- wave-autonomous GEMM stage: ONE wave, 32 rows, full output width in 4-tile passes ----
// A (32 rows x K) loaded FULLY into registers before any LDS write -> in-place in/out safe
// by data-dependency (writes' source regs depend on all reads). No block barrier needed.
// mfma(w_frag, a_frag): D col=l15 = row (mt tile), D row'=quad*4+r = out column.
template<int K, int C, int INO, int OUTO, bool RELU>
__device__ __forceinline__ void stage_rs(
    const unsigned short* __restrict__ Wt,     // [C][K] bf16, global (L2-hot)
    const float* __restrict__ bias,            // [C]
    unsigned short* buf,                       // LDS, pitch PA
    int l15, int quad)
{
  constexpr int KC = K / 32;
  constexpr int CP = C / 64;                   // 64-col passes (acc[2][4] = 32 VGPR)
  bf16x8 areg[2][KC];
  #pragma unroll
  for (int mt = 0; mt < 2; ++mt)
    #pragma unroll
    for (int kc = 0; kc < KC; ++kc)
      areg[mt][kc] = __builtin_bit_cast(bf16x8,
          *(const short8*)&buf[(mt * 16 + l15) * PA + INO + kc * 32 + quad * 8]);
  #pragma unroll
  for (int cp = 0; cp < CP; ++cp) {
    f32x4 acc[2][4];
    #pragma unroll
    for (int mt = 0; mt < 2; ++mt)
      #pragma unroll
      for (int nt = 0; nt < 4; ++nt) acc[mt][nt] = (f32x4){0.f, 0.f, 0.f, 0.f};
    #pragma unroll
    for (int kc = 0; kc < KC; ++kc) {
      bf16x8 w[4];
      #pragma unroll
      for (int nt = 0; nt < 4; ++nt)
        w[nt] = __builtin_bit_cast(bf16x8,
            *(const short8*)(Wt + (size_t)(cp * 64 + nt * 16 + l15) * K + kc * 32 + quad * 8));
      __builtin_amdgcn_s_setprio(1);
      #pragma unroll
      for (int mt = 0; mt < 2; ++mt)
        #pragma unroll
        for (int nt = 0; nt < 4; ++nt)
          acc[mt][nt] = __builtin_amdgcn_mfma_f32_16x16x32_bf16(w[nt], areg[mt][kc], acc[mt][nt], 0, 0, 0);
      __builtin_amdgcn_s_setprio(0);
    }
    #pragma unroll
    for (int mt = 0; mt < 2; ++mt)
      #pragma unroll
      for (int nt = 0; nt < 4; ++nt) {
        const int cbase = cp * 64 + nt * 16 + quad * 4;
        const f32x4 bs = *(const f32x4*)&bias[cbase];
        unsigned short h[4];
        #pragma unroll
        for (int r = 0; r < 4; ++r) {
          float y = acc[mt][nt][r] + bs[r];
          if (RELU) y = fmaxf(y, 0.f);
          h[r] = f2bf(y);
        }
        uint2 pk; pk.x = (unsigned)h[0] | ((unsigned)h[1] << 16);
        pk.y = (unsigned)h[2] | ((unsigned)h[3] << 16);
        *(uint2*)&buf[(mt * 16 + l15) * PA + OUTO + cbase] = pk;   // ds_write_b64
      }
  }
}

// ---------------- wave-autonomous MLP: 7500 blocks x 1 wave x 32 rows; no cross-wave deps ----
// Removes ALL block-wide lockstep (the measured fixed cost): barriers here are single-wave
// (near-free). 9 independent waves/CU (LDS-bound) overlap each other's weight-load latency.
// Cost: each wave reads full weights per 32 rows (2x L2 traffic, still L2-resident).
__global__ __launch_bounds__(64) void mlp_pool_kernel(
    const float* __restrict__ ptfea, const float* __restrict__ xyz, const int* __restrict__ shuf,
    const unsigned long long* __restrict__ plist64,
    const unsigned* __restrict__ offv, const unsigned* __restrict__ cnt,
    const int* __restrict__ ptlab, const unsigned* __restrict__ unqvals,
    const float* __restrict__ s0, const float* __restrict__ t0,
    const float* __restrict__ w1e, const float* __restrict__ be1,
    const unsigned short* __restrict__ w2t, const float* __restrict__ be2,
    const unsigned short* __restrict__ w3t, const float* __restrict__ be3,
    const unsigned short* __restrict__ w4t, const float* __restrict__ b4,
    const unsigned short* __restrict__ wct, const float* __restrict__ bc,
    unsigned short* __restrict__ partials, float* __restrict__ out_pooled,
    float* __restrict__ out_lab)
{
  __shared__ __align__(16) unsigned short buf[32 * PA];
  __shared__ int s_seg[32];
  __shared__ int s_jr[32];
  __shared__ unsigned short s_runs[16];              // (r<<8)|e for runs with len>1
  __shared__ unsigned char s_lead[32], s_comp[32];
  const int lane = threadIdx.x;                      // one wave: 0..63
  const int l15 = lane & 15, quad = lane >> 4;
  const int row0 = blockIdx.x * 32;

  int jr = 0, sg = 0;
  if (lane < 32) {
    const unsigned long long v = plist64[(size_t)row0 + lane];
    jr = (int)(unsigned)v; sg = (int)(unsigned)(v >> 32);
    s_jr[lane] = jr; s_seg[lane] = sg;
  }
  __syncthreads();                                   // single-wave barrier: meta visible

  // ---- run analysis via ballot (lanes 0..31 carry rows) + labels for complete runs ----
  bool lead = false; int e = 0; bool comp = false;
  if (lane < 32) lead = (lane == 0) || (sg != s_seg[lane - 1]);
  const unsigned long long mm = __ballot(lead);
  if (lead) {
    unsigned long long rest = (mm | (1ull << 32)) & ~(((unsigned long long)2 << lane) - 1ull);
    e = __builtin_ctzll(rest);                       // run end (<=32)
    comp = (offv[(unsigned)sg] == (unsigned)(row0 + lane)) &&
           (offv[(unsigned)sg] + cnt[(unsigned)sg] == (unsigned)(row0 + e));
  }
  if (lane < 32) { s_lead[lane] = lead ? 1 : 0; s_comp[lane] = comp ? 1 : 0; }
  const int alast = 63 - __builtin_clzll(mm);        // last leader row (bit 0 always set)
  if (comp) {                                        // label argmax: first max = smallest label
    int bestl;
    if (e - lane == 1) bestl = ptlab[jr];
    else {
      int bestc = 0; bestl = 32;
      for (int i = lane; i < e; ++i) {
        const int li = ptlab[s_jr[i]];
        int cc = 0;
        for (int k2 = lane; k2 < e; ++k2) cc += (ptlab[s_jr[k2]] == li) ? 1 : 0;
        if (cc > bestc || (cc == bestc && li < bestl)) { bestc = cc; bestl = li; }
      }
    }
    out_lab[unqvals[(unsigned)sg]] = (float)bestl;
  }
  const bool multi = lead && (e - lane) > 1;
  const unsigned long long mmu = __ballot(multi);
  if (multi) s_runs[(int)__popcll(mmu & ((1ull << lane) - 1ull))] = (unsigned short)((lane << 8) | e);
  const int nrun = (int)__popcll(mmu);

  // ---- stage 0: features + bn0 fold + layer1 (scalar fp32); 2 lanes/row, 32 ch each ----
  {
    const int r = lane >> 1, part = lane & 1;
    const int sj = shuf[s_jr[r]];
    const float PI_F = 3.14159265358979323846f;
    const float minb[3] = {0.0f, -PI_F, -4.0f};
    const float maxb[3] = {50.0f, PI_F, 2.0f};
    const float gm1[3]  = {479.0f, 359.0f, 31.0f};
    float x0[9];
    #pragma unroll
    for (int d = 0; d < 3; ++d) {
      float itv = (maxb[d] - minb[d]) / gm1[d];
      float x   = xyz[(size_t)sj * 3 + d];
      float cl  = fminf(fmaxf(x, minb[d]), maxb[d]);
      float fi  = floorf((cl - minb[d]) / itv);
      float center = (fi + 0.5f) * itv + minb[d];
      x0[d] = (x - center) * s0[d] + t0[d];           // bn0 folded
    }
    #pragma unroll
    for (int d = 0; d < 6; ++d) x0[3 + d] = ptfea[(size_t)sj * 6 + d] * s0[3 + d] + t0[3 + d];
    unsigned short h[32];
    #pragma unroll
    for (int ci = 0; ci < 32; ++ci) {
      float acc = be1[part * 32 + ci];
      #pragma unroll
      for (int k = 0; k < 9; ++k) acc += x0[k] * w1e[k * 64 + part * 32 + ci];
      h[ci] = f2bf(fmaxf(acc, 0.0f));
    }
    #pragma unroll
    for (int i = 0; i < 4; ++i)
      *(short8*)&buf[r * PA + part * 32 + i * 8] = *(short8*)&h[i * 8];
  }
  __syncthreads();

  // ---- L2 [64->128] cols 0 -> 64..191; L3 [128->256] 64..191 -> 0..255; L4 in-place ----
  stage_rs< 64, 128,  0, 64, true >(w2t, be2, buf, l15, quad);
  __syncthreads();
  stage_rs<128, 256, 64,  0, true >(w3t, be3, buf, l15, quad);
  __syncthreads();
  stage_rs<256, 256,  0,  0, false>(w4t, b4,  buf, l15, quad);
  __syncthreads();

  // ---- sparse fixup: per multi-run, 64 lanes x 4 cols compute run max into leader row ----
  for (int i = 0; i < nrun; ++i) {
    const int re = s_runs[i];
    const int r = re >> 8, ee = re & 255;
    #pragma unroll
    for (int k = 0; k < 4; ++k) {
      const int c = lane + 64 * k;
      float m = bf2f(buf[r * PA + c]);
      for (int rr = r + 1; rr < ee; ++rr) m = fmaxf(m, bf2f(buf[rr * PA + c]));
      buf[r * PA + c] = f2bf(m);
    }
  }
  __syncthreads();

  // ---- boundary partials (first/last incomplete runs; rows 0 and alast are leaders) ----
  {
    const size_t b2 = (size_t)blockIdx.x * 2;
    #pragma unroll
    for (int k = 0; k < 4; ++k) {
      const int c = lane + 64 * k;
      if (!s_comp[0])     partials[b2 * 256 + c]       = buf[0 * PA + c];
      if (!s_comp[alast]) partials[(b2 + 1) * 256 + c] = buf[alast * PA + c];
    }
  }

  // ---- compression: pooled rows @ wct^T; two 16-row halves; swapped-D -> float4 stores ----
  {
    const unsigned short* wp = wct + l15 * 256 + quad * 8;
    bf16x8 wv[8];
    #pragma unroll
    for (int kc = 0; kc < 8; ++kc)
      wv[kc] = __builtin_bit_cast(bf16x8, *(const short8*)(wp + kc * 32));
    #pragma unroll
    for (int half = 0; half < 2; ++half) {
      f32x4 acc = (f32x4){0.f, 0.f, 0.f, 0.f};
      #pragma unroll
      for (int kc = 0; kc < 8; ++kc) {
        bf16x8 x = __builtin_bit_cast(bf16x8,
            *(const short8*)&buf[(half * 16 + l15) * PA + kc * 32 + quad * 8]);
        acc = __builtin_amdgcn_mfma_f32_16x16x32_bf16(wv[kc], x, acc, 0, 0, 0);
      }
      const int r1 = half * 16 + l15;                // pooled row (D col = l15)
      if (s_lead[r1] && s_comp[r1]) {
        const f32x4 bcv = *(const f32x4*)&bc[quad * 4];
        f32x4 v;
        #pragma unroll
        for (int r = 0; r < 4; ++r) v[r] = fmaxf(acc[r] + bcv[r], 0.f);   // cols quad*4+r
        *(f32x4*)&out_pooled[(size_t)s_seg[r1] * 16 + quad * 4] = v;
      }
    }
  }
}

// ---------------- merge block-spanning segments from partials (+ their labels), 32-row tiles ----
__global__ __launch_bounds__(256) void merge_kernel(
    const unsigned long long* __restrict__ plist64,
    const unsigned* __restrict__ offv, const unsigned* __restrict__ cnt,
    const unsigned short* __restrict__ partials,
    const int* __restrict__ ptlab, const unsigned* __restrict__ unqvals,
    const float* __restrict__ wc, const float* __restrict__ bc,
    float* __restrict__ out_pooled, float* __restrict__ out_lab)
{
  __shared__ float pooled[256];
  __shared__ float psum[256];
  const int b = blockIdx.x;
  const unsigned s = (unsigned)(plist64[(size_t)b * 32 + 31] >> 32);
  const unsigned o = offv[s], e = o + cnt[s];
  if ((o >> 5) != (unsigned)b) return;              // owner = block where segment starts
  if (e <= (unsigned)(b + 1) * 32) return;          // doesn't span a boundary
  const int B1 = (int)((e - 1) >> 5);
  const int c = threadIdx.x;
  float m = bf2f(partials[((size_t)2 * b + 1) * 256 + c]);    // head partial (last run of b)
  for (int bb = b + 1; bb <= B1; ++bb)
    m = fmaxf(m, bf2f(partials[(size_t)2 * bb * 256 + c]));   // tails (first run of bb)
  pooled[c] = m;
  __syncthreads();
  const int co = c & 15, kg = c >> 4;
  float p = 0.f;
  #pragma unroll
  for (int k = kg * 16; k < kg * 16 + 16; ++k) p += pooled[k] * wc[k * 16 + co];
  psum[c] = p;
  __syncthreads();
  if (c < 16) {
    float acc = bc[c];
    #pragma unroll
    for (int g = 0; g < 16; ++g) acc += psum[g * 16 + c];
    out_pooled[(size_t)s * 16 + c] = fmaxf(acc, 0.f);
  }
  if (c == 0) {                                     // label argmax over the spanning segment
    int bestc = 0, bestl = 32;
    for (unsigned i = o; i < e; ++i) {
      const int li = ptlab[(unsigned)plist64[i]];
      int cc = 0;
      for (unsigned k2 = o; k2 < e; ++k2) cc += (ptlab[(unsigned)plist64[k2]] == li) ? 1 : 0;
      if (cc > bestc || (cc == bestc && li < bestl)) { bestc = cc; bestl = li; }
    }
    out_lab[unqvals[s]] = (float)bestl;
  }
}

extern "C" void kernel_launch(void* const* d_in, const int* in_sizes, int n_in,
                              void* d_out, int out_size, void* d_ws, size_t ws_size,
                              hipStream_t stream)
{
  const float* pt_fea = (const float*)d_in[0];
  const float* xyz    = (const float*)d_in[1];
  const int*   bidx   = (const int*)d_in[2];
  const int*   ptlab  = (const int*)d_in[3];
  const int*   shuf   = (const int*)d_in[4];
  const float* bng0 = (const float*)d_in[5],  *bnb0 = (const float*)d_in[6],  *bnm0 = (const float*)d_in[7],  *bnv0 = (const float*)d_in[8];
  const float* bng1 = (const float*)d_in[9],  *bnb1 = (const float*)d_in[10], *bnm1 = (const float*)d_in[11], *bnv1 = (const float*)d_in[12];
  const float* bng2 = (const float*)d_in[13], *bnb2 = (const float*)d_in[14], *bnm2 = (const float*)d_in[15], *bnv2 = (const float*)d_in[16];
  const float* bng3 = (const float*)d_in[17], *bnb3 = (const float*)d_in[18], *bnm3 = (const float*)d_in[19], *bnv3 = (const float*)d_in[20];
  const float* w1 = (const float*)d_in[21], *b1 = (const float*)d_in[22];
  const float* w2 = (const float*)d_in[23], *b2 = (const float*)d_in[24];
  const float* w3 = (const float*)d_in[25], *b3 = (const float*)d_in[26];
  const float* w4 = (const float*)d_in[27], *b4 = (const float*)d_in[28];
  const float* wc = (const float*)d_in[29], *bc = (const float*)d_in[30];

  float* out        = (float*)d_out;                // outputs int64/f32/int32 -> float32 buffer
  float* out_unq    = out;                          // [240000]
  float* out_pooled = out + 240000;                 // [240000,16]
  float* out_lab    = out + 4080000;                // [2,480,360,32]
  float* out_cat    = out + 15139200;               // [240000,4]

  char* wsb = (char*)d_ws;
  size_t o = 0;
  auto alloc = [&](size_t bytes) -> void* { void* p = wsb + o; o = (o + bytes + 255) & ~(size_t)255; return p; };
  // zero-init region (single memset): bitmap | cnt
  unsigned long long* bitmap = (unsigned long long*)alloc((size_t)NWORDS * 8);
  unsigned* cnt    = (unsigned*)alloc((size_t)N_PTS * 4);
  const size_t zero_bytes = o;
  float* s0  = (float*)alloc(9 * 4);
  float* t0  = (float*)alloc(9 * 4);
  float* w1e = (float*)alloc(576 * 4);
  float* be1 = (float*)alloc(64 * 4);
  float* be2 = (float*)alloc(128 * 4);
  float* be3 = (float*)alloc(256 * 4);
  unsigned short* w2t = (unsigned short*)alloc(8192 * 2);
  unsigned short* w3t = (unsigned short*)alloc(32768 * 2);
  unsigned short* w4t = (unsigned short*)alloc(65536 * 2);
  unsigned short* wct = (unsigned short*)alloc(4096 * 2);
  unsigned* flatkeys = (unsigned*)alloc((size_t)N_PTS * 4);
  unsigned* unq_inv  = (unsigned*)alloc((size_t)N_PTS * 4);
  unsigned* unqvals  = (unsigned*)alloc((size_t)N_PTS * 4);
  unsigned* offv     = (unsigned*)alloc((size_t)N_PTS * 4);
  unsigned* cur      = (unsigned*)alloc((size_t)N_PTS * 4);
  unsigned long long* plist64 = (unsigned long long*)alloc((size_t)N_PTS * 8);
  unsigned* wordpref = (unsigned*)alloc((size_t)NWORDS * 4);
  unsigned* bsumA    = (unsigned*)alloc(NB_WORD * 4);
  unsigned* bsumB    = (unsigned*)alloc(NB_PT * 4);
  unsigned short* partials = (unsigned short*)alloc((size_t)NSEG_BLK * 2 * 256 * 2);
  // total ~18 MB

  hipMemsetAsync(bitmap, 0, zero_bytes, stream);
  hipMemsetAsync(out_lab, 0, (size_t)NV * 4, stream);       // float 0.0f == all-zero bytes

  prep_vox_kernel<<<256 + NB_PT, 256, 0, stream>>>(
      bng0, bnb0, bnm0, bnv0, bng1, bnb1, bnm1, bnv1,
      bng2, bnb2, bnm2, bnv2, bng3, bnb3, bnm3, bnv3,
      w1, b1, w2, b2, w3, b3, w4, wc,
      s0, t0, w1e, be1, be2, be3, w2t, w3t, w4t, wct,
      xyz, bidx, flatkeys, bitmap, out_cat, out_unq);
  reduce_words<<<NB_WORD, 256, 0, stream>>>(bitmap, bsumA);
  scatter_unq<<<NB_WORD, 256, 0, stream>>>(bitmap, bsumA, wordpref, unqvals, out_unq);
  inv_kernel<<<NB_PT, 256, 0, stream>>>(flatkeys, bitmap, wordpref, unq_inv, cnt);
  reduce_cnt<<<NB_PT, 256, 0, stream>>>(cnt, bsumB);
  scan_cnt<<<NB_PT, 256, 0, stream>>>(cnt, bsumB, offv, cur);
  plist_fill_kernel<<<NB_PT, 256, 0, stream>>>(unq_inv, cur, plist64, cnt, bc, out_pooled);
  mlp_pool_kernel<<<NSEG_BLK, 64, 0, stream>>>(pt_fea, xyz, shuf, plist64, offv, cnt,
                                               ptlab, unqvals,
                                               s0, t0, w1e, be1, w2t, be2, w3t, be3, w4t, b4,
                                               wct, bc, partials, out_pooled, out_lab);
  merge_kernel<<<NSEG_BLK, 256, 0, stream>>>(plist64, offv, cnt, partials,
                                             ptlab, unqvals, wc, bc, out_pooled, out_lab);
}